// Round 7
// baseline (192.749 us; speedup 1.0000x reference)
//
#include <hip/hip_runtime.h>

// ---------- types ----------
typedef __bf16 bf16x8 __attribute__((ext_vector_type(8)));
typedef float f32x4 __attribute__((ext_vector_type(4)));
typedef unsigned short u16x8 __attribute__((ext_vector_type(8)));

__device__ inline unsigned short f2bf(float f) {
  union { float f; unsigned u; } a; a.f = f;
  return (unsigned short)((a.u + 0x7fffu + ((a.u >> 16) & 1u)) >> 16); // RNE
}
__device__ inline float bf2f(unsigned short h) {
  union { unsigned u; float f; } a; a.u = ((unsigned)h) << 16;
  return a.f;
}

// ---------- fp32 -> bf16 conversion for Wq,Wk,Wv only (12 MB) ----------
__global__ __launch_bounds__(256) void cvtW(const float* __restrict__ Wq,
                                            const float* __restrict__ Wk,
                                            const float* __restrict__ Wv,
                                            unsigned short* __restrict__ Wb) {
  int i = blockIdx.x * 256 + threadIdx.x;   // 786432 float4 groups
  int idx = i >> 18;                        // 262144 float4 per W
  int off = i & 262143;
  const float* s = (idx == 0) ? Wq : ((idx == 1) ? Wk : Wv);
  float4 v = ((const float4*)s)[off];
  ushort4 o;
  o.x = f2bf(v.x); o.y = f2bf(v.y); o.z = f2bf(v.z); o.w = f2bf(v.w);
  ((ushort4*)(Wb + idx * 1048576))[off] = o;
}

// =====================================================================
// bf16 GEMM C[M,N] = A[M,K] @ B[N,K]^T, rolling one-barrier-per-K-tile
// schedule (r4 structure, best measured). 512 thr = 8 waves, per-wave
// WMW x WNW, BK=64, LDS double-buffered, T2 XOR swizzle (0 conflicts).
// Frag reads one quadrant ahead w/ counted lgkm (waves de-phase; LDS
// drain overlaps other waves' MFMA). Staging via global_load_lds.
// ACVT=true (proj only, 256x128 where regs fit -- r5 lesson: 256x256
// spills): A fp32 in global, staged via reg-relay global_load_dwordx4
// -> cvt bf16 -> swizzled ds_write_b128; kills the Xb HBM round-trip.
// r5 race fixed: prologue waits vmcnt(2) = ldA(0)+stageB(0) retired.
// Grid notes: proj 768 WGs = 3 balanced rounds (384@256sq = 1.5 rounds
// = 25% tail bubble, measured slower); QK/PV 256 WGs = 1 round.
// =====================================================================
#define EPI_PROJ 0
#define EPI_SCALE 1
#define EPI_OUT 2

struct GP {
  const unsigned short* A;
  const unsigned short* B;
  unsigned short* C;            // bf16 out (EPI_SCALE) or float* (EPI_OUT)
  unsigned short* outQ; unsigned short* outK; unsigned short* outV;
  const float* biasQ; const float* biasK; const float* biasV;
  const float* Af0; const float* Af1; const float* Af2; // fp32 A per z (ACVT)
  long long batchA, batchB, batchC;
  int lda, ldb, ldc, K;
  float scale;
};

#define G2L(gp, lp) __builtin_amdgcn_global_load_lds( \
    (const __attribute__((address_space(1))) void*)(gp), \
    (__attribute__((address_space(3))) void*)(lp), 16, 0, 0)

#define MFMA_(d, a, b) d = __builtin_amdgcn_mfma_f32_16x16x32_bf16(a, b, d, 0, 0, 0)
#define SB0() __builtin_amdgcn_sched_barrier(0)
#define LGKM(n) do { asm volatile("s_waitcnt lgkmcnt(" #n ")" ::: "memory"); SB0(); } while (0)
#define VMC(n) do { asm volatile("s_waitcnt vmcnt(" #n ")" ::: "memory"); SB0(); } while (0)

template<int BM, int BN, int WMW, int WNW, int EPI, bool ACVT>
__global__ __launch_bounds__(512, 2) void gemm2(GP p) {
  constexpr int WAVES_N = BN / WNW;
  constexpr int AMF = WMW / 16;           // A frags (m) per wave
  constexpr int BNF = WNW / 16;           // B frags (n) per wave
  constexpr int AH = AMF / 2, BH = BNF / 2;
  constexpr int AF_N = AH * 2;            // reads per A-half set (8 or 4)
  constexpr int NBA = BM / 64, NBB = BN / 64; // staging chunks per thread
  static_assert((BM / WMW) * WAVES_N == 8, "8 waves");
  static_assert(BNF == 4, "lgkm immediates assume BNF==4");
  static_assert(!ACVT || (NBA == 4 && NBB == 2), "ACVT vmcnt immediates");

  extern __shared__ char smem[];          // 2*(BM+BN)*128 bytes
  char* smA = smem;                       // buf b at b*BM*128
  char* smB = smem + 2 * BM * 128;        // buf b at b*BN*128

  const int tid = threadIdx.x;
  const int lane = tid & 63;
  const int wid = tid >> 6;
  const int wm = wid / WAVES_N, wn = wid % WAVES_N;

  // bijective XCD-aware block swizzle (m204)
  const int gx = gridDim.x, gy = gridDim.y;
  const int nwg = gx * gy * (int)gridDim.z;
  int orig = blockIdx.x + gx * (blockIdx.y + gy * blockIdx.z);
  int qq = nwg >> 3, rr_ = nwg & 7;
  int xcd = orig & 7, sl = orig >> 3;
  int wg = (xcd < rr_ ? xcd * (qq + 1) : rr_ * (qq + 1) + (xcd - rr_) * qq) + sl;
  int bx = wg % gx;
  int t2 = wg / gx;
  int by = t2 % gy;
  int z  = t2 / gy;

  const int m0 = by * BM, n0 = bx * BN;

  const long long lda2 = (long long)p.lda * 2;
  const long long ldb2 = (long long)p.ldb * 2;
  const char* Bbase = (const char*)(p.B + (long long)z * p.batchB) + (long long)n0 * ldb2;

  // staging: thread covers LDS linear slot c*8192 + tid*16;
  // row = c*64 + tid/8, source col pre-inverse-swizzled
  const int trow = tid >> 3;
  const int cs = (((tid & 7) ^ (trow & 7)) << 4);
  const char* srcB = Bbase + (long long)trow * ldb2 + cs;

  const char* srcA = nullptr;
  const float* AzF = nullptr;
  if constexpr (ACVT) {
    const float* Az = (z == 0) ? p.Af0 : ((z == 1) ? p.Af1 : p.Af2);
    AzF = Az + (long long)(m0 + trow) * p.lda + (tid & 7) * 8;
  } else {
    const char* Abase = (const char*)(p.A + (long long)z * p.batchA) + (long long)m0 * lda2;
    srcA = Abase + (long long)trow * lda2 + cs;
  }

  const int NT = p.K >> 6;

  // swizzled ds_read offsets
  const int aRowB = ((wm * WMW + (lane & 15)) << 7);
  const int bRowB = ((wn * WNW + (lane & 15)) << 7);
  const int csw = (lane & 7) << 4;
  const int ck0 = (((lane >> 4) << 4)) ^ csw;
  const int ck1 = ((((lane >> 4) << 4)) | 64) ^ csw;

  f32x4 acc[AMF][BNF];
#pragma unroll
  for (int i = 0; i < AMF; ++i)
#pragma unroll
    for (int j = 0; j < BNF; ++j) acc[i][j] = (f32x4){0.f, 0.f, 0.f, 0.f};

  bf16x8 aLo[AH][2], aHi[AH][2], bLo[BH][2], bHi[BH][2];
  float4 areg[ACVT ? 2 * NBA : 1];

  auto stage = [&](int t) {                 // full tile via G2L (bf16 A+B)
    char* dA = smA + (t & 1) * (BM * 128) + (tid << 4);
    char* dB = smB + (t & 1) * (BN * 128) + (tid << 4);
    const char* sA = srcA + (long long)t * 128;
    const char* sB = srcB + (long long)t * 128;
#pragma unroll
    for (int c = 0; c < NBA; ++c) G2L(sA + (long long)c * (lda2 << 6), dA + c * 8192);
#pragma unroll
    for (int c = 0; c < NBB; ++c) G2L(sB + (long long)c * (ldb2 << 6), dB + c * 8192);
  };
  auto stageB = [&](int t) {                // B only (ACVT path)
    char* dB = smB + (t & 1) * (BN * 128) + (tid << 4);
    const char* sB = srcB + (long long)t * 128;
#pragma unroll
    for (int c = 0; c < NBB; ++c) G2L(sB + (long long)c * (ldb2 << 6), dB + c * 8192);
  };
  auto ldA = [&](int t) {                   // fp32 A loads -> areg (coalesced)
    const float* s0 = AzF + (long long)t * 64;
#pragma unroll
    for (int c = 0; c < NBA; ++c) {
      const float* s = s0 + (long long)c * 64 * p.lda;
      areg[2 * c]     = *(const float4*)(s);
      areg[2 * c + 1] = *(const float4*)(s + 4);
    }
  };
  auto wrA = [&](int t) {                   // cvt + swizzled ds_write_b128
    char* dA = smA + (t & 1) * (BM * 128) + (trow << 7) + cs;
#pragma unroll
    for (int c = 0; c < NBA; ++c) {
      float4 lo = areg[2 * c], hi = areg[2 * c + 1];
      union { bf16x8 v; uint4 q; } u;
      u.v = (bf16x8){(__bf16)lo.x, (__bf16)lo.y, (__bf16)lo.z, (__bf16)lo.w,
                     (__bf16)hi.x, (__bf16)hi.y, (__bf16)hi.z, (__bf16)hi.w};
      *(uint4*)(dA + c * 8192) = u.q;
    }
  };
  auto readAh = [&](int t, int half, bf16x8 (&dst)[AH][2]) {
    const char* ra = smA + (t & 1) * (BM * 128) + aRowB + half * (AH * 2048);
#pragma unroll
    for (int mi = 0; mi < AH; ++mi) {
      dst[mi][0] = *(const bf16x8*)(ra + mi * 2048 + ck0);
      dst[mi][1] = *(const bf16x8*)(ra + mi * 2048 + ck1);
    }
  };
  auto readBh = [&](int t, int half, bf16x8 (&dst)[BH][2]) {
    const char* rb = smB + (t & 1) * (BN * 128) + bRowB + half * (BH * 2048);
#pragma unroll
    for (int ni = 0; ni < BH; ++ni) {
      dst[ni][0] = *(const bf16x8*)(rb + ni * 2048 + ck0);
      dst[ni][1] = *(const bf16x8*)(rb + ni * 2048 + ck1);
    }
  };
  auto quad = [&](int qa, int qb, bf16x8 (&A)[AH][2], bf16x8 (&B)[BH][2]) {
    __builtin_amdgcn_s_setprio(1);
#pragma unroll
    for (int mi = 0; mi < AH; ++mi)
#pragma unroll
      for (int ni = 0; ni < BH; ++ni) {
        MFMA_(acc[qa * AH + mi][qb * BH + ni], A[mi][0], B[ni][0]);
        MFMA_(acc[qa * AH + mi][qb * BH + ni], A[mi][1], B[ni][1]);
      }
    __builtin_amdgcn_s_setprio(0);
  };

  // ---- prologue ----
  if constexpr (ACVT) {
    ldA(0); stageB(0); stageB(1);   // 8 + 2 + 2 in flight
    VMC(2);                         // ldA(0)+stageB(0) retired (in-order)
    wrA(0); LGKM(0);
    __builtin_amdgcn_s_barrier();
    ldA(1);                         // 8 in flight across iter t=0
  } else {
    stage(0); stage(1);
    if constexpr (NBA + NBB == 8) VMC(8); else VMC(6);  // tile0 landed
    __builtin_amdgcn_s_barrier();
  }
  readAh(0, 0, aLo); readBh(0, 0, bLo);
  SB0();

  for (int t = 0; t < NT; ++t) {
    readAh(t, 1, aHi);                 // aHi
    SB0();
    if constexpr (AF_N == 8) LGKM(8); else LGKM(4);  // aLo,bLo ready
    quad(0, 0, aLo, bLo);
    readBh(t, 1, bHi);                 // bHi
    SB0();
    LGKM(4);                           // aHi ready
    quad(1, 0, aHi, bLo);
    LGKM(0);                           // bHi ready
    quad(0, 1, aLo, bHi);
    quad(1, 1, aHi, bHi);
    VMC(0);                            // tile t+1 staging landed
    if constexpr (ACVT) { if (t + 1 < NT) { wrA(t + 1); } LGKM(0); }
    __builtin_amdgcn_s_barrier();      // all waves done reading tile t
    if (t + 2 < NT) {
      if constexpr (ACVT) { ldA(t + 2); stageB(t + 2); }
      else stage(t + 2);
    }
    if (t + 1 < NT) { readAh(t + 1, 0, aLo); readBh(t + 1, 0, bLo); }
    SB0();
  }

  // ---------- epilogue ----------
  const int c0 = lane & 15;
  const int r0 = (lane >> 4) << 2;
  if constexpr (EPI == EPI_SCALE) {
    unsigned short* Cz = p.C + (long long)z * p.batchC;
#pragma unroll
    for (int mi = 0; mi < AMF; ++mi) {
      const int grow = m0 + wm * WMW + (mi << 4) + r0;
#pragma unroll
      for (int ni = 0; ni < BNF; ++ni) {
        const int gcol = n0 + wn * WNW + (ni << 4) + c0;
#pragma unroll
        for (int rr = 0; rr < 4; ++rr)
          Cz[(long long)(grow + rr) * p.ldc + gcol] = f2bf(acc[mi][ni][rr] * p.scale);
      }
    }
  } else if constexpr (EPI == EPI_OUT) {
    float* Cz = (float*)p.C + (long long)z * p.batchC;
#pragma unroll
    for (int mi = 0; mi < AMF; ++mi) {
      const int grow = m0 + wm * WMW + (mi << 4) + r0;
#pragma unroll
      for (int ni = 0; ni < BNF; ++ni) {
        const int gcol = n0 + wn * WNW + (ni << 4) + c0;
#pragma unroll
        for (int rr = 0; rr < 4; ++rr)
          Cz[(long long)(grow + rr) * p.ldc + gcol] = acc[mi][ni][rr] * p.scale;
      }
    }
  } else { // EPI_PROJ
    if (z < 2) {
      unsigned short* O = (z == 0) ? p.outQ : p.outK;
      const float* bias = (z == 0) ? p.biasQ : p.biasK;
#pragma unroll
      for (int mi = 0; mi < AMF; ++mi) {
        const int grow = m0 + wm * WMW + (mi << 4) + r0;
#pragma unroll
        for (int ni = 0; ni < BNF; ++ni) {
          const int gcol = n0 + wn * WNW + (ni << 4) + c0;
          const float bb = bias[gcol];
#pragma unroll
          for (int rr = 0; rr < 4; ++rr)
            O[(long long)(grow + rr) * 1024 + gcol] = f2bf(acc[mi][ni][rr] + bb);
        }
      }
    } else { // v projection, transposed out: vT[b][d][s]
#pragma unroll
      for (int mi = 0; mi < AMF; ++mi) {
        const int grow = m0 + wm * WMW + (mi << 4) + r0;
        const int bb = grow >> 11, s = grow & 2047;
#pragma unroll
        for (int ni = 0; ni < BNF; ++ni) {
          const int d = n0 + wn * WNW + (ni << 4) + c0;
          const float ba = p.biasV[d];
          ushort4 pk;
          pk.x = f2bf(acc[mi][ni][0] + ba);
          pk.y = f2bf(acc[mi][ni][1] + ba);
          pk.z = f2bf(acc[mi][ni][2] + ba);
          pk.w = f2bf(acc[mi][ni][3] + ba);
          *(ushort4*)(p.outV + ((long long)bb << 21) + (long long)d * 2048 + s) = pk;
        }
      }
    }
  }
}

// ---------- row softmax over S[4][2048][2048] (bf16, in place) ----------
__global__ __launch_bounds__(256) void softmax_rows(unsigned short* __restrict__ S) {
  const size_t row = blockIdx.x;
  unsigned short* pp = S + row * 2048;
  const int t = threadIdx.x, lane = t & 63, wave = t >> 6;
  u16x8 h = ((const u16x8*)pp)[t];
  float x[8];
#pragma unroll
  for (int j = 0; j < 8; ++j) x[j] = bf2f(h[j]);
  float m = x[0];
#pragma unroll
  for (int j = 1; j < 8; ++j) m = fmaxf(m, x[j]);
#pragma unroll
  for (int off = 32; off >= 1; off >>= 1) m = fmaxf(m, __shfl_xor(m, off, 64));
  __shared__ float rmax[4], rsum[4];
  if (lane == 0) rmax[wave] = m;
  __syncthreads();
  m = fmaxf(fmaxf(rmax[0], rmax[1]), fmaxf(rmax[2], rmax[3]));
  float e[8], sum = 0.f;
#pragma unroll
  for (int j = 0; j < 8; ++j) { e[j] = __expf(x[j] - m); sum += e[j]; }
#pragma unroll
  for (int off = 32; off >= 1; off >>= 1) sum += __shfl_xor(sum, off, 64);
  if (lane == 0) rsum[wave] = sum;
  __syncthreads();
  sum = rsum[0] + rsum[1] + rsum[2] + rsum[3];
  const float inv = 1.f / sum;
  u16x8 o;
#pragma unroll
  for (int j = 0; j < 8; ++j) o[j] = f2bf(e[j] * inv);
  ((u16x8*)pp)[t] = o;
}

// ---------- launch ----------
extern "C" void kernel_launch(void* const* d_in, const int* in_sizes, int n_in,
                              void* d_out, int out_size, void* d_ws, size_t ws_size,
                              hipStream_t stream) {
  const float* q  = (const float*)d_in[0];
  const float* k  = (const float*)d_in[1];
  const float* v  = (const float*)d_in[2];
  const float* Wq = (const float*)d_in[3];
  const float* bq = (const float*)d_in[4];
  const float* Wk = (const float*)d_in[5];
  const float* bk = (const float*)d_in[6];
  const float* Wv = (const float*)d_in[7];
  const float* bv = (const float*)d_in[8];

  // workspace (u16 elems): S 32MB, Wb 6MB, qb 16MB, kb 16MB, vT 16MB = 86MB
  unsigned short* S  = (unsigned short*)d_ws;
  unsigned short* Wb = S + 16777216;
  unsigned short* qb = Wb + 3145728;
  unsigned short* kb = qb + 8388608;
  unsigned short* vT = kb + 8388608;

  (void)hipFuncSetAttribute((const void*)gemm2<256,128,64,64,EPI_PROJ,true>,
      hipFuncAttributeMaxDynamicSharedMemorySize, 98304);
  (void)hipFuncSetAttribute((const void*)gemm2<256,256,128,64,EPI_SCALE,false>,
      hipFuncAttributeMaxDynamicSharedMemorySize, 131072);
  (void)hipFuncSetAttribute((const void*)gemm2<256,128,64,64,EPI_OUT,false>,
      hipFuncAttributeMaxDynamicSharedMemorySize, 98304);

  cvtW<<<3072, 256, 0, stream>>>(Wq, Wk, Wv, Wb);

  // fused q/k/v projections: per z, M=8192, N=1024, K=1024 (768 WGs,
  // 3 balanced rounds); fp32 A converted in-kernel (ACVT)
  GP gp{};
  gp.B = Wb;  gp.batchB = 1048576; gp.ldb = 1024;
  gp.Af0 = q; gp.Af1 = k; gp.Af2 = v; gp.lda = 1024;
  gp.outQ = qb; gp.outK = kb; gp.outV = vT;
  gp.biasQ = bq; gp.biasK = bk; gp.biasV = bv;
  gp.K = 1024; gp.scale = 1.f;
  gemm2<256,128,64,64,EPI_PROJ,true><<<dim3(8, 32, 3), 512, 98304, stream>>>(gp);

  // scores = q @ k^T * scale : per batch M=2048, N=2048, K=1024 (256 WGs)
  GP gs{};
  gs.A = qb; gs.batchA = 2097152; gs.lda = 1024;
  gs.B = kb; gs.batchB = 2097152; gs.ldb = 1024;
  gs.C = S;  gs.batchC = 4194304; gs.ldc = 2048;
  gs.K = 1024; gs.scale = 0.03125f;
  gemm2<256,256,128,64,EPI_SCALE,false><<<dim3(8, 8, 4), 512, 131072, stream>>>(gs);

  softmax_rows<<<8192, 256, 0, stream>>>(S);

  // out = P @ V : M=2048, N=1024, K=2048 per batch (256 WGs)
  GP gv{};
  gv.A = S;  gv.batchA = 4194304; gv.lda = 2048;
  gv.B = vT; gv.batchB = 2097152; gv.ldb = 2048;
  gv.C = (unsigned short*)d_out; gv.batchC = 2097152; gv.ldc = 1024;
  gv.K = 2048; gv.scale = 1.f;
  gemm2<256,128,64,64,EPI_OUT,false><<<dim3(8, 8, 4), 512, 98304, stream>>>(gv);
}

// Round 8
// 185.081 us; speedup vs baseline: 1.0414x; 1.0414x over previous
//
#include <hip/hip_runtime.h>

// ---------- types ----------
typedef __bf16 bf16x8 __attribute__((ext_vector_type(8)));
typedef float f32x4 __attribute__((ext_vector_type(4)));
typedef unsigned short u16x8 __attribute__((ext_vector_type(8)));

__device__ inline unsigned short f2bf(float f) {
  union { float f; unsigned u; } a; a.f = f;
  return (unsigned short)((a.u + 0x7fffu + ((a.u >> 16) & 1u)) >> 16); // RNE
}
__device__ inline float bf2f(unsigned short h) {
  union { unsigned u; float f; } a; a.u = ((unsigned)h) << 16;
  return a.f;
}

// ---------- fp32 -> bf16 conversion (query,key,value,Wq,Wk,Wv) ----------
struct CvtArgs {
  const float* src[6];
  unsigned short* dst[6];
};

__global__ __launch_bounds__(256) void cvt6(CvtArgs a) {
  long long i = (long long)blockIdx.x * 256 + threadIdx.x; // one float4 each
  int idx; long long off;
  if (i < 6291456LL) { idx = (int)(i >> 21); off = i & ((1LL << 21) - 1); }
  else { long long j = i - 6291456LL; idx = 3 + (int)(j >> 18); off = j & ((1LL << 18) - 1); }
  float4 v = ((const float4*)a.src[idx])[off];
  ushort4 o;
  o.x = f2bf(v.x); o.y = f2bf(v.y); o.z = f2bf(v.z); o.w = f2bf(v.w);
  ((ushort4*)a.dst[idx])[off] = o;
}

// =====================================================================
// bf16 GEMM C[M,N] = A[M,K] @ B[N,K]^T, rolling one-barrier-per-K-tile
// schedule. KT=64: r4's proven 256^2 8-wave config (QK).
// KT=32: NEW 128^2 4-wave config for 4 WGs/CU co-residency (proj, PV):
//   LDS 32KB (2buf x (BM+BN) x 64B), row-PAIRED layout: line L (128B)
//   holds rows {2L,2L+1}; 16B slot p of line L stores logical slot
//   sigma = p ^ (L&7)  (sigma>>2 = row parity, sigma&3 = k-16B-group).
//   Max 2-way bank aliasing on ds_read_b128 (free, m136). Staged via
//   inverse-permuted global source (both-sides rule).
// =====================================================================
#define EPI_PROJ 0
#define EPI_SCALE 1
#define EPI_OUT 2

struct GP {
  const unsigned short* A;
  const unsigned short* B;
  unsigned short* C;            // bf16 out (EPI_SCALE) or float* (EPI_OUT)
  unsigned short* outQ; unsigned short* outK; unsigned short* outV;
  const float* biasQ; const float* biasK; const float* biasV;
  long long batchA, batchB, batchC;
  int lda, ldb, ldc, K;
  float scale;
};

#define G2L(gp, lp) __builtin_amdgcn_global_load_lds( \
    (const __attribute__((address_space(1))) void*)(gp), \
    (__attribute__((address_space(3))) void*)(lp), 16, 0, 0)

#define MFMA_(d, a, b) d = __builtin_amdgcn_mfma_f32_16x16x32_bf16(a, b, d, 0, 0, 0)
#define SB0() __builtin_amdgcn_sched_barrier(0)
#define LGKM(n) do { asm volatile("s_waitcnt lgkmcnt(" #n ")" ::: "memory"); SB0(); } while (0)
#define VMC(n) do { asm volatile("s_waitcnt vmcnt(" #n ")" ::: "memory"); SB0(); } while (0)

template<int BM, int BN, int WMW, int WNW, int KT, int EPI>
__global__ __launch_bounds__((BM/WMW)*(BN/WNW)*64, ((BM/WMW)*(BN/WNW) == 8) ? 2 : 4)
void gemm2(GP p) {
  constexpr int NWN = BN / WNW;
  constexpr int THREADS = (BM / WMW) * NWN * 64;
  constexpr int AMF = WMW / 16, BNF = WNW / 16;
  constexpr int AH = AMF / 2, BH = BNF / 2;
  constexpr int KTB = KT * 2;             // bytes per row K-window
  constexpr int ABUF = BM * KTB, BBUF = BN * KTB;
  constexpr int CHUNK = THREADS * 16;     // bytes staged per G2L instr
  constexpr int NBA = ABUF / CHUNK, NBB = BBUF / CHUNK;
  static_assert(BNF == 4 && BH == 2, "wave shape");
  static_assert(KT == 64 || (AH == 2), "KT32 only for 64-wide wave M");

  extern __shared__ char smem[];
  char* smA = smem;                       // buf b at b*ABUF
  char* smB = smem + 2 * ABUF;            // buf b at b*BBUF

  const int tid = threadIdx.x;
  const int lane = tid & 63;
  const int wid = tid >> 6;
  const int wm = wid / NWN, wn = wid % NWN;

  // bijective XCD-aware block swizzle (m204)
  const int gx = gridDim.x, gy = gridDim.y;
  const int nwg = gx * gy * (int)gridDim.z;
  int orig = blockIdx.x + gx * (blockIdx.y + gy * blockIdx.z);
  int qq = nwg >> 3, rr_ = nwg & 7;
  int xcd = orig & 7, sl = orig >> 3;
  int wg = (xcd < rr_ ? xcd * (qq + 1) : rr_ * (qq + 1) + (xcd - rr_) * qq) + sl;
  int bx = wg % gx;
  int t2 = wg / gx;
  int by = t2 % gy;
  int z  = t2 / gy;

  const int m0 = by * BM, n0 = bx * BN;

  const long long lda2 = (long long)p.lda * 2;
  const long long ldb2 = (long long)p.ldb * 2;
  const char* Abase = (const char*)(p.A + (long long)z * p.batchA) + (long long)m0 * lda2;
  const char* Bbase = (const char*)(p.B + (long long)z * p.batchB) + (long long)n0 * ldb2;

  // ---- staging source (per-thread), inverse-permuted for read swizzle ----
  const char* srcA; const char* srcB;
  if constexpr (KT == 64) {
    const int trow = tid >> 3;
    const int cs = (((tid & 7) ^ (trow & 7)) << 4);
    srcA = Abase + (long long)trow * lda2 + cs;
    srcB = Bbase + (long long)trow * ldb2 + cs;
  } else {
    const int line = tid >> 3, s = tid & 7;
    const int sg = s ^ (line & 7);               // logical slot
    const int srow = 2 * line + (sg >> 2);
    const int scol = (sg & 3) << 4;
    srcA = Abase + (long long)srow * lda2 + scol;
    srcB = Bbase + (long long)srow * ldb2 + scol;
  }

  const int NT = p.K / KT;

  // ---- swizzled ds_read offsets ----
  int aOff, bOff, ck0 = 0, ck1 = 0;
  if constexpr (KT == 64) {
    aOff = ((wm * WMW + (lane & 15)) << 7);
    bOff = ((wn * WNW + (lane & 15)) << 7);
    const int csw = (lane & 7) << 4;
    ck0 = (((lane >> 4) << 4)) ^ csw;
    ck1 = ((((lane >> 4) << 4)) | 64) ^ csw;
  } else {
    const int kh = lane >> 4;
    const int Ra = wm * WMW + (lane & 15);
    const int Rb = wn * WNW + (lane & 15);
    aOff = ((Ra >> 1) << 7) + (((((Ra & 1) << 2) | kh) ^ ((Ra >> 1) & 7)) << 4);
    bOff = ((Rb >> 1) << 7) + (((((Rb & 1) << 2) | kh) ^ ((Rb >> 1) & 7)) << 4);
  }

  f32x4 acc[AMF][BNF];
#pragma unroll
  for (int i = 0; i < AMF; ++i)
#pragma unroll
    for (int j = 0; j < BNF; ++j) acc[i][j] = (f32x4){0.f, 0.f, 0.f, 0.f};

  bf16x8 aLo[AH][2], aHi[AH][2], bLo[BH][2], bHi[BH][2];

  auto stage = [&](int t) {
    char* dA = smA + (t & 1) * ABUF + (tid << 4);
    char* dB = smB + (t & 1) * BBUF + (tid << 4);
    const char* sA = srcA + (long long)t * KTB;
    const char* sB = srcB + (long long)t * KTB;
#pragma unroll
    for (int c = 0; c < NBA; ++c) G2L(sA + (long long)c * 64 * lda2, dA + c * CHUNK);
#pragma unroll
    for (int c = 0; c < NBB; ++c) G2L(sB + (long long)c * 64 * ldb2, dB + c * CHUNK);
  };
  auto readAh = [&](int t, int half, bf16x8 (&dst)[AH][2]) {
    const char* ra = smA + (t & 1) * ABUF;
#pragma unroll
    for (int mi = 0; mi < AH; ++mi) {
      if constexpr (KT == 64) {
        dst[mi][0] = *(const bf16x8*)(ra + aOff + ((half * AH + mi) << 11) + ck0);
        dst[mi][1] = *(const bf16x8*)(ra + aOff + ((half * AH + mi) << 11) + ck1);
      } else {
        dst[mi][0] = *(const bf16x8*)(ra + aOff + (half * AH + mi) * 1024);
      }
    }
  };
  auto readBh = [&](int t, int half, bf16x8 (&dst)[BH][2]) {
    const char* rb = smB + (t & 1) * BBUF;
#pragma unroll
    for (int ni = 0; ni < BH; ++ni) {
      if constexpr (KT == 64) {
        dst[ni][0] = *(const bf16x8*)(rb + bOff + ((half * BH + ni) << 11) + ck0);
        dst[ni][1] = *(const bf16x8*)(rb + bOff + ((half * BH + ni) << 11) + ck1);
      } else {
        dst[ni][0] = *(const bf16x8*)(rb + bOff + (half * BH + ni) * 1024);
      }
    }
  };
  auto quad = [&](int qa, int qb, bf16x8 (&A)[AH][2], bf16x8 (&B)[BH][2]) {
    __builtin_amdgcn_s_setprio(1);
#pragma unroll
    for (int mi = 0; mi < AH; ++mi)
#pragma unroll
      for (int ni = 0; ni < BH; ++ni) {
        MFMA_(acc[qa * AH + mi][qb * BH + ni], A[mi][0], B[ni][0]);
        if constexpr (KT == 64)
          MFMA_(acc[qa * AH + mi][qb * BH + ni], A[mi][1], B[ni][1]);
      }
    __builtin_amdgcn_s_setprio(0);
  };

  // ---- prologue: stage tiles 0,1; confirm tile0; pre-read lo sets ----
  stage(0); stage(1);
  if constexpr (NBA + NBB == 8) VMC(8); else VMC(4);
  __builtin_amdgcn_s_barrier();
  readAh(0, 0, aLo); readBh(0, 0, bLo);
  SB0();

  for (int t = 0; t < NT; ++t) {
    readAh(t, 1, aHi);
    SB0();
    if constexpr (KT == 64) { if constexpr (AH == 4) LGKM(8); else LGKM(4); }
    else LGKM(2);                        // aLo,bLo ready
    quad(0, 0, aLo, bLo);
    readBh(t, 1, bHi);
    SB0();
    if constexpr (KT == 64) LGKM(4); else LGKM(2);   // aHi ready
    quad(1, 0, aHi, bLo);
    LGKM(0);                             // bHi ready
    quad(0, 1, aLo, bHi);
    quad(1, 1, aHi, bHi);
    VMC(0);                              // stage(t+1) landed
    __builtin_amdgcn_s_barrier();        // all waves done reading tile t
    if (t + 2 < NT) stage(t + 2);        // into buffer (t&1), now free
    if (t + 1 < NT) { readAh(t + 1, 0, aLo); readBh(t + 1, 0, bLo); }
    SB0();
  }

  // ---------- epilogue ----------
  const int c0 = lane & 15;
  const int r0 = (lane >> 4) << 2;
  if constexpr (EPI == EPI_SCALE) {
    unsigned short* Cz = p.C + (long long)z * p.batchC;
#pragma unroll
    for (int mi = 0; mi < AMF; ++mi) {
      const int grow = m0 + wm * WMW + (mi << 4) + r0;
#pragma unroll
      for (int ni = 0; ni < BNF; ++ni) {
        const int gcol = n0 + wn * WNW + (ni << 4) + c0;
#pragma unroll
        for (int rr = 0; rr < 4; ++rr)
          Cz[(long long)(grow + rr) * p.ldc + gcol] = f2bf(acc[mi][ni][rr] * p.scale);
      }
    }
  } else if constexpr (EPI == EPI_OUT) {
    float* Cz = (float*)p.C + (long long)z * p.batchC;
#pragma unroll
    for (int mi = 0; mi < AMF; ++mi) {
      const int grow = m0 + wm * WMW + (mi << 4) + r0;
#pragma unroll
      for (int ni = 0; ni < BNF; ++ni) {
        const int gcol = n0 + wn * WNW + (ni << 4) + c0;
#pragma unroll
        for (int rr = 0; rr < 4; ++rr)
          Cz[(long long)(grow + rr) * p.ldc + gcol] = acc[mi][ni][rr] * p.scale;
      }
    }
  } else { // EPI_PROJ
    if (z < 2) {
      unsigned short* O = (z == 0) ? p.outQ : p.outK;
      const float* bias = (z == 0) ? p.biasQ : p.biasK;
#pragma unroll
      for (int mi = 0; mi < AMF; ++mi) {
        const int grow = m0 + wm * WMW + (mi << 4) + r0;
#pragma unroll
        for (int ni = 0; ni < BNF; ++ni) {
          const int gcol = n0 + wn * WNW + (ni << 4) + c0;
          const float bb = bias[gcol];
#pragma unroll
          for (int rr = 0; rr < 4; ++rr)
            O[(long long)(grow + rr) * 1024 + gcol] = f2bf(acc[mi][ni][rr] + bb);
        }
      }
    } else { // v projection, transposed out: vT[b][d][s]
#pragma unroll
      for (int mi = 0; mi < AMF; ++mi) {
        const int grow = m0 + wm * WMW + (mi << 4) + r0;
        const int bb = grow >> 11, s = grow & 2047;
#pragma unroll
        for (int ni = 0; ni < BNF; ++ni) {
          const int d = n0 + wn * WNW + (ni << 4) + c0;
          const float ba = p.biasV[d];
          ushort4 pk;
          pk.x = f2bf(acc[mi][ni][0] + ba);
          pk.y = f2bf(acc[mi][ni][1] + ba);
          pk.z = f2bf(acc[mi][ni][2] + ba);
          pk.w = f2bf(acc[mi][ni][3] + ba);
          *(ushort4*)(p.outV + ((long long)bb << 21) + (long long)d * 2048 + s) = pk;
        }
      }
    }
  }
}

// ---------- row softmax over S[4][2048][2048] (bf16, in place) ----------
__global__ __launch_bounds__(256) void softmax_rows(unsigned short* __restrict__ S) {
  const size_t row = blockIdx.x;
  unsigned short* pp = S + row * 2048;
  const int t = threadIdx.x, lane = t & 63, wave = t >> 6;
  u16x8 h = ((const u16x8*)pp)[t];
  float x[8];
#pragma unroll
  for (int j = 0; j < 8; ++j) x[j] = bf2f(h[j]);
  float m = x[0];
#pragma unroll
  for (int j = 1; j < 8; ++j) m = fmaxf(m, x[j]);
#pragma unroll
  for (int off = 32; off >= 1; off >>= 1) m = fmaxf(m, __shfl_xor(m, off, 64));
  __shared__ float rmax[4], rsum[4];
  if (lane == 0) rmax[wave] = m;
  __syncthreads();
  m = fmaxf(fmaxf(rmax[0], rmax[1]), fmaxf(rmax[2], rmax[3]));
  float e[8], sum = 0.f;
#pragma unroll
  for (int j = 0; j < 8; ++j) { e[j] = __expf(x[j] - m); sum += e[j]; }
#pragma unroll
  for (int off = 32; off >= 1; off >>= 1) sum += __shfl_xor(sum, off, 64);
  if (lane == 0) rsum[wave] = sum;
  __syncthreads();
  sum = rsum[0] + rsum[1] + rsum[2] + rsum[3];
  const float inv = 1.f / sum;
  u16x8 o;
#pragma unroll
  for (int j = 0; j < 8; ++j) o[j] = f2bf(e[j] * inv);
  ((u16x8*)pp)[t] = o;
}

// ---------- launch ----------
extern "C" void kernel_launch(void* const* d_in, const int* in_sizes, int n_in,
                              void* d_out, int out_size, void* d_ws, size_t ws_size,
                              hipStream_t stream) {
  const float* q  = (const float*)d_in[0];
  const float* k  = (const float*)d_in[1];
  const float* v  = (const float*)d_in[2];
  const float* Wq = (const float*)d_in[3];
  const float* bq = (const float*)d_in[4];
  const float* Wk = (const float*)d_in[5];
  const float* bk = (const float*)d_in[6];
  const float* Wv = (const float*)d_in[7];
  const float* bv = (const float*)d_in[8];

  // workspace (u16 elems): Xb 48MB (S 32MB overlays it later), Wb 6MB,
  // qb 16MB, kb 16MB, vT 16MB -> 102MB total
  unsigned short* Xb = (unsigned short*)d_ws;
  unsigned short* Wb = Xb + 25165824;
  unsigned short* qb = Wb + 3145728;
  unsigned short* kb = qb + 8388608;
  unsigned short* vT = kb + 8388608;
  unsigned short* S  = Xb;

  (void)hipFuncSetAttribute((const void*)gemm2<128,128,64,64,32,EPI_PROJ>,
      hipFuncAttributeMaxDynamicSharedMemorySize, 32768);
  (void)hipFuncSetAttribute((const void*)gemm2<256,256,128,64,64,EPI_SCALE>,
      hipFuncAttributeMaxDynamicSharedMemorySize, 131072);
  (void)hipFuncSetAttribute((const void*)gemm2<128,128,64,64,32,EPI_OUT>,
      hipFuncAttributeMaxDynamicSharedMemorySize, 32768);

  CvtArgs ca;
  ca.src[0] = q;  ca.src[1] = k;  ca.src[2] = v;
  ca.src[3] = Wq; ca.src[4] = Wk; ca.src[5] = Wv;
  ca.dst[0] = Xb;            ca.dst[1] = Xb + 8388608; ca.dst[2] = Xb + 16777216;
  ca.dst[3] = Wb;            ca.dst[4] = Wb + 1048576; ca.dst[5] = Wb + 2097152;
  cvt6<<<27648, 256, 0, stream>>>(ca);

  // fused q/k/v projections: per z, M=8192, N=1024, K=1024
  // 128^2/4-wave/BK32: 1536 WGs at 4 WGs/CU (de-phased co-residency)
  GP gp{};
  gp.A = Xb;  gp.batchA = 8388608; gp.lda = 1024;
  gp.B = Wb;  gp.batchB = 1048576; gp.ldb = 1024;
  gp.outQ = qb; gp.outK = kb; gp.outV = vT;
  gp.biasQ = bq; gp.biasK = bk; gp.biasV = bv;
  gp.K = 1024; gp.scale = 1.f;
  gemm2<128,128,64,64,32,EPI_PROJ><<<dim3(8, 64, 3), 256, 32768, stream>>>(gp);

  // scores = q @ k^T * scale : per batch M=2048, N=2048, K=1024 (256 WGs)
  GP gs{};
  gs.A = qb; gs.batchA = 2097152; gs.lda = 1024;
  gs.B = kb; gs.batchB = 2097152; gs.ldb = 1024;
  gs.C = S;  gs.batchC = 4194304; gs.ldc = 2048;
  gs.K = 1024; gs.scale = 0.03125f;
  gemm2<256,256,128,64,64,EPI_SCALE><<<dim3(8, 8, 4), 512, 131072, stream>>>(gs);

  softmax_rows<<<8192, 256, 0, stream>>>(S);

  // out = P @ V : M=2048, N=1024, K=2048 per batch (512 WGs, 4/CU)
  GP gv{};
  gv.A = S;  gv.batchA = 4194304; gv.lda = 2048;
  gv.B = vT; gv.batchB = 2097152; gv.ldb = 2048;
  gv.C = (unsigned short*)d_out; gv.batchC = 2097152; gv.ldc = 1024;
  gv.K = 2048; gv.scale = 1.f;
  gemm2<128,128,64,64,32,EPI_OUT><<<dim3(8, 16, 4), 256, 32768, stream>>>(gv);
}

// Round 9
// 182.900 us; speedup vs baseline: 1.0538x; 1.0119x over previous
//
#include <hip/hip_runtime.h>

// ---------- types ----------
typedef __bf16 bf16x8 __attribute__((ext_vector_type(8)));
typedef float f32x4 __attribute__((ext_vector_type(4)));
typedef unsigned short u16x8 __attribute__((ext_vector_type(8)));

__device__ inline unsigned short f2bf(float f) {
  union { float f; unsigned u; } a; a.f = f;
  return (unsigned short)((a.u + 0x7fffu + ((a.u >> 16) & 1u)) >> 16); // RNE
}
__device__ inline float bf2f(unsigned short h) {
  union { unsigned u; float f; } a; a.u = ((unsigned)h) << 16;
  return a.f;
}

// ---------- fp32 -> bf16 conversion (query,key,value,Wq,Wk,Wv) ----------
struct CvtArgs {
  const float* src[6];
  unsigned short* dst[6];
};

__global__ __launch_bounds__(256) void cvt6(CvtArgs a) {
  long long i = (long long)blockIdx.x * 256 + threadIdx.x; // one float4 each
  int idx; long long off;
  if (i < 6291456LL) { idx = (int)(i >> 21); off = i & ((1LL << 21) - 1); }
  else { long long j = i - 6291456LL; idx = 3 + (int)(j >> 18); off = j & ((1LL << 18) - 1); }
  float4 v = ((const float4*)a.src[idx])[off];
  ushort4 o;
  o.x = f2bf(v.x); o.y = f2bf(v.y); o.z = f2bf(v.z); o.w = f2bf(v.w);
  ((ushort4*)a.dst[idx])[off] = o;
}

// =====================================================================
// bf16 GEMM C[M,N] = A[M,K] @ B[N,K]^T.  BK=32, 512 thr = 8 waves,
// per-wave WMW x WNW, THREE LDS buffers, deep pipeline:
//   stage(t+2) issued at TOP of tile t (buf (t+2)%3 = buf (t-1)%3,
//   whose reads completed before the end-of-(t-1) barrier);
//   mid-loop wait = vmcnt(NBA+NBB) -> tile t+1 confirmed, t+2 stays in
//   flight (never drain to 0 mid-loop, T4/m218); ~2 tiles of latency
//   cover vs 0 in the r4 drain-0 schedule.
// LDS: row-paired layout (r8-verified, 0 conflicts): 128B line L holds
// rows {2L,2L+1}; 16B slot s stores logical slot s^(L&7); staged via
// inverse-permuted global source (both-sides rule), read via same XOR.
// Rolling frag reads one quadrant ahead, counted lgkm (4,2,0).
// =====================================================================
#define EPI_PROJ 0
#define EPI_SCALE 1
#define EPI_OUT 2

struct GP {
  const unsigned short* A;
  const unsigned short* B;
  unsigned short* C;            // bf16 out (EPI_SCALE) or float* (EPI_OUT)
  unsigned short* outQ; unsigned short* outK; unsigned short* outV;
  const float* biasQ; const float* biasK; const float* biasV;
  long long batchA, batchB, batchC;
  int lda, ldb, ldc, K;
  float scale;
};

#define G2L(gp, lp) __builtin_amdgcn_global_load_lds( \
    (const __attribute__((address_space(1))) void*)(gp), \
    (__attribute__((address_space(3))) void*)(lp), 16, 0, 0)

#define MFMA_(d, a, b) d = __builtin_amdgcn_mfma_f32_16x16x32_bf16(a, b, d, 0, 0, 0)
#define SB0() __builtin_amdgcn_sched_barrier(0)
#define LGKM(n) do { asm volatile("s_waitcnt lgkmcnt(" #n ")" ::: "memory"); SB0(); } while (0)
#define VMC(n) do { asm volatile("s_waitcnt vmcnt(" #n ")" ::: "memory"); SB0(); } while (0)

template<int BM, int BN, int WMW, int WNW, int MINW, int EPI>
__global__ __launch_bounds__(512, MINW) void gemm3(GP p) {
  constexpr int NWN = BN / WNW;
  constexpr int AMF = WMW / 16, BNF = WNW / 16;
  constexpr int AH = AMF / 2, BH = BNF / 2;
  constexpr int ABUF = BM * 64, BBUF = BN * 64;   // bytes per buffer (BK=32)
  constexpr int NBA = ABUF / 8192, NBB = BBUF / 8192; // G2L per thread
  static_assert((BM / WMW) * NWN == 8, "8 waves");
  static_assert(BNF == 4, "BH==2 assumed");
  static_assert(NBA >= 1 && NBB >= 1, "chunking");

  extern __shared__ char smem[];
  char* smA = smem;                       // buf b at b*ABUF
  char* smB = smem + 3 * ABUF;            // buf b at b*BBUF

  const int tid = threadIdx.x;
  const int lane = tid & 63;
  const int wid = tid >> 6;
  const int wm = wid / NWN, wn = wid % NWN;

  // bijective XCD-aware block swizzle (m204)
  const int gx = gridDim.x, gy = gridDim.y;
  const int nwg = gx * gy * (int)gridDim.z;
  int orig = blockIdx.x + gx * (blockIdx.y + gy * blockIdx.z);
  int qq = nwg >> 3, rr_ = nwg & 7;
  int xcd = orig & 7, sl = orig >> 3;
  int wg = (xcd < rr_ ? xcd * (qq + 1) : rr_ * (qq + 1) + (xcd - rr_) * qq) + sl;
  int bx = wg % gx;
  int t2 = wg / gx;
  int by = t2 % gy;
  int z  = t2 / gy;

  const int m0 = by * BM, n0 = bx * BN;

  const long long lda2 = (long long)p.lda * 2;
  const long long ldb2 = (long long)p.ldb * 2;
  const char* Abase = (const char*)(p.A + (long long)z * p.batchA) + (long long)m0 * lda2;
  const char* Bbase = (const char*)(p.B + (long long)z * p.batchB) + (long long)n0 * ldb2;

  // staging source, inverse-permuted for the row-paired swizzle:
  // dest line = tid>>3 (+64c), slot s = tid&7; logical sg = s^(line&7);
  // source row = 2*line + (sg>>2), col16 = sg&3.
  const int line = tid >> 3;
  const int sg = (tid & 7) ^ (line & 7);
  const long long srowA = 2 * line + (sg >> 2);
  const int scol = (sg & 3) << 4;
  const char* srcA = Abase + srowA * lda2 + scol;
  const char* srcB = Bbase + srowA * ldb2 + scol;

  const int NT = p.K >> 5;

  // swizzled ds_read offsets (row-paired): row R, k-group kh=lane>>4:
  // byte = (R>>1)<<7 + ((((R&1)<<2)|kh) ^ ((R>>1)&7))<<4
  const int kh = lane >> 4;
  const int Ra = wm * WMW + (lane & 15);
  const int Rb = wn * WNW + (lane & 15);
  const int aOff = ((Ra >> 1) << 7) + (((((Ra & 1) << 2) | kh) ^ ((Ra >> 1) & 7)) << 4);
  const int bOff = ((Rb >> 1) << 7) + (((((Rb & 1) << 2) | kh) ^ ((Rb >> 1) & 7)) << 4);

  f32x4 acc[AMF][BNF];
#pragma unroll
  for (int i = 0; i < AMF; ++i)
#pragma unroll
    for (int j = 0; j < BNF; ++j) acc[i][j] = (f32x4){0.f, 0.f, 0.f, 0.f};

  bf16x8 aLo[AH], aHi[AH], bLo[BH], bHi[BH];

  auto stage = [&](int t, int b) {
    char* dA = smA + b * ABUF + (tid << 4);
    char* dB = smB + b * BBUF + (tid << 4);
    const char* sA = srcA + (long long)t * 64;
    const char* sB = srcB + (long long)t * 64;
#pragma unroll
    for (int c = 0; c < NBA; ++c) G2L(sA + (long long)c * 128 * lda2, dA + c * 8192);
#pragma unroll
    for (int c = 0; c < NBB; ++c) G2L(sB + (long long)c * 128 * ldb2, dB + c * 8192);
  };
  auto readAh = [&](int b, int half, bf16x8 (&dst)[AH]) {
    const char* ra = smA + b * ABUF + aOff + half * (AH << 10);
#pragma unroll
    for (int mi = 0; mi < AH; ++mi)
      dst[mi] = *(const bf16x8*)(ra + (mi << 10));
  };
  auto readBh = [&](int b, int half, bf16x8 (&dst)[BH]) {
    const char* rb = smB + b * BBUF + bOff + half * (BH << 10);
#pragma unroll
    for (int ni = 0; ni < BH; ++ni)
      dst[ni] = *(const bf16x8*)(rb + (ni << 10));
  };
  auto quad = [&](int qa, int qb, bf16x8 (&A)[AH], bf16x8 (&B)[BH]) {
    __builtin_amdgcn_s_setprio(1);
#pragma unroll
    for (int mi = 0; mi < AH; ++mi)
#pragma unroll
      for (int ni = 0; ni < BH; ++ni)
        MFMA_(acc[qa * AH + mi][qb * BH + ni], A[mi], B[ni]);
    __builtin_amdgcn_s_setprio(0);
  };

  // ---- prologue: stage 0,1; confirm tile0 (tile1 stays in flight) ----
  stage(0, 0); stage(1, 1);
  if constexpr (NBA + NBB == 4) VMC(4); else VMC(3);
  __builtin_amdgcn_s_barrier();
  readAh(0, 0, aLo); readBh(0, 0, bLo);
  SB0();

  int b0 = 0, b1 = 1, b2 = 2; // buf of t, t+1, t+2
  for (int t = 0; t < NT; ++t) {
    if (t + 2 < NT) stage(t + 2, b2);  // overlaps entire tile body
    readAh(b0, 1, aHi);
    SB0();
    LGKM(4);                           // aLo,bLo ready
    quad(0, 0, aLo, bLo);
    readBh(b0, 1, bHi);
    SB0();
    LGKM(2);                           // aHi ready
    quad(1, 0, aHi, bLo);
    LGKM(0);                           // bHi ready
    quad(0, 1, aLo, bHi);
    quad(1, 1, aHi, bHi);
    if (t + 2 < NT) {                  // t+1 landed; t+2 stays in flight
      if constexpr (NBA + NBB == 4) VMC(4); else VMC(3);
    } else {
      VMC(0);
    }
    __builtin_amdgcn_s_barrier();      // all waves done reading buf b0
    if (t + 1 < NT) { readAh(b1, 0, aLo); readBh(b1, 0, bLo); }
    SB0();
    int tmp = b0; b0 = b1; b1 = b2; b2 = tmp;
  }

  // ---------- epilogue ----------
  const int c0 = lane & 15;
  const int r0 = (lane >> 4) << 2;
  if constexpr (EPI == EPI_SCALE) {
    unsigned short* Cz = p.C + (long long)z * p.batchC;
#pragma unroll
    for (int mi = 0; mi < AMF; ++mi) {
      const int grow = m0 + wm * WMW + (mi << 4) + r0;
#pragma unroll
      for (int ni = 0; ni < BNF; ++ni) {
        const int gcol = n0 + wn * WNW + (ni << 4) + c0;
#pragma unroll
        for (int rr = 0; rr < 4; ++rr)
          Cz[(long long)(grow + rr) * p.ldc + gcol] = f2bf(acc[mi][ni][rr] * p.scale);
      }
    }
  } else if constexpr (EPI == EPI_OUT) {
    float* Cz = (float*)p.C + (long long)z * p.batchC;
#pragma unroll
    for (int mi = 0; mi < AMF; ++mi) {
      const int grow = m0 + wm * WMW + (mi << 4) + r0;
#pragma unroll
      for (int ni = 0; ni < BNF; ++ni) {
        const int gcol = n0 + wn * WNW + (ni << 4) + c0;
#pragma unroll
        for (int rr = 0; rr < 4; ++rr)
          Cz[(long long)(grow + rr) * p.ldc + gcol] = acc[mi][ni][rr] * p.scale;
      }
    }
  } else { // EPI_PROJ
    if (z < 2) {
      unsigned short* O = (z == 0) ? p.outQ : p.outK;
      const float* bias = (z == 0) ? p.biasQ : p.biasK;
#pragma unroll
      for (int mi = 0; mi < AMF; ++mi) {
        const int grow = m0 + wm * WMW + (mi << 4) + r0;
#pragma unroll
        for (int ni = 0; ni < BNF; ++ni) {
          const int gcol = n0 + wn * WNW + (ni << 4) + c0;
          const float bb = bias[gcol];
#pragma unroll
          for (int rr = 0; rr < 4; ++rr)
            O[(long long)(grow + rr) * 1024 + gcol] = f2bf(acc[mi][ni][rr] + bb);
        }
      }
    } else { // v projection, transposed out: vT[b][d][s]
#pragma unroll
      for (int mi = 0; mi < AMF; ++mi) {
        const int grow = m0 + wm * WMW + (mi << 4) + r0;
        const int bb = grow >> 11, s = grow & 2047;
#pragma unroll
        for (int ni = 0; ni < BNF; ++ni) {
          const int d = n0 + wn * WNW + (ni << 4) + c0;
          const float ba = p.biasV[d];
          ushort4 pk;
          pk.x = f2bf(acc[mi][ni][0] + ba);
          pk.y = f2bf(acc[mi][ni][1] + ba);
          pk.z = f2bf(acc[mi][ni][2] + ba);
          pk.w = f2bf(acc[mi][ni][3] + ba);
          *(ushort4*)(p.outV + ((long long)bb << 21) + (long long)d * 2048 + s) = pk;
        }
      }
    }
  }
}

// ---------- row softmax over S[4][2048][2048] (bf16, in place) ----------
__global__ __launch_bounds__(256) void softmax_rows(unsigned short* __restrict__ S) {
  const size_t row = blockIdx.x;
  unsigned short* pp = S + row * 2048;
  const int t = threadIdx.x, lane = t & 63, wave = t >> 6;
  u16x8 h = ((const u16x8*)pp)[t];
  float x[8];
#pragma unroll
  for (int j = 0; j < 8; ++j) x[j] = bf2f(h[j]);
  float m = x[0];
#pragma unroll
  for (int j = 1; j < 8; ++j) m = fmaxf(m, x[j]);
#pragma unroll
  for (int off = 32; off >= 1; off >>= 1) m = fmaxf(m, __shfl_xor(m, off, 64));
  __shared__ float rmax[4], rsum[4];
  if (lane == 0) rmax[wave] = m;
  __syncthreads();
  m = fmaxf(fmaxf(rmax[0], rmax[1]), fmaxf(rmax[2], rmax[3]));
  float e[8], sum = 0.f;
#pragma unroll
  for (int j = 0; j < 8; ++j) { e[j] = __expf(x[j] - m); sum += e[j]; }
#pragma unroll
  for (int off = 32; off >= 1; off >>= 1) sum += __shfl_xor(sum, off, 64);
  if (lane == 0) rsum[wave] = sum;
  __syncthreads();
  sum = rsum[0] + rsum[1] + rsum[2] + rsum[3];
  const float inv = 1.f / sum;
  u16x8 o;
#pragma unroll
  for (int j = 0; j < 8; ++j) o[j] = f2bf(e[j] * inv);
  ((u16x8*)pp)[t] = o;
}

// ---------- launch ----------
extern "C" void kernel_launch(void* const* d_in, const int* in_sizes, int n_in,
                              void* d_out, int out_size, void* d_ws, size_t ws_size,
                              hipStream_t stream) {
  const float* q  = (const float*)d_in[0];
  const float* k  = (const float*)d_in[1];
  const float* v  = (const float*)d_in[2];
  const float* Wq = (const float*)d_in[3];
  const float* bq = (const float*)d_in[4];
  const float* Wk = (const float*)d_in[5];
  const float* bk = (const float*)d_in[6];
  const float* Wv = (const float*)d_in[7];
  const float* bv = (const float*)d_in[8];

  // workspace (u16 elems): Xb 48MB (S 32MB overlays it later), Wb 6MB,
  // qb 16MB, kb 16MB, vT 16MB -> 102MB total
  unsigned short* Xb = (unsigned short*)d_ws;
  unsigned short* Wb = Xb + 25165824;
  unsigned short* qb = Wb + 3145728;
  unsigned short* kb = qb + 8388608;
  unsigned short* vT = kb + 8388608;
  unsigned short* S  = Xb;

  (void)hipFuncSetAttribute((const void*)gemm3<256,128,64,64,4,EPI_PROJ>,
      hipFuncAttributeMaxDynamicSharedMemorySize, 73728);
  (void)hipFuncSetAttribute((const void*)gemm3<256,256,128,64,2,EPI_SCALE>,
      hipFuncAttributeMaxDynamicSharedMemorySize, 98304);
  (void)hipFuncSetAttribute((const void*)gemm3<256,128,64,64,2,EPI_OUT>,
      hipFuncAttributeMaxDynamicSharedMemorySize, 73728);

  CvtArgs ca;
  ca.src[0] = q;  ca.src[1] = k;  ca.src[2] = v;
  ca.src[3] = Wq; ca.src[4] = Wk; ca.src[5] = Wv;
  ca.dst[0] = Xb;            ca.dst[1] = Xb + 8388608; ca.dst[2] = Xb + 16777216;
  ca.dst[3] = Wb;            ca.dst[4] = Wb + 1048576; ca.dst[5] = Wb + 2097152;
  cvt6<<<27648, 256, 0, stream>>>(ca);

  // fused q/k/v projections: per z, M=8192, N=1024, K=1024
  // 256x128, 768 WGs; launch_bounds(512,4) targets 2 WGs/CU
  GP gp{};
  gp.A = Xb;  gp.batchA = 8388608; gp.lda = 1024;
  gp.B = Wb;  gp.batchB = 1048576; gp.ldb = 1024;
  gp.outQ = qb; gp.outK = kb; gp.outV = vT;
  gp.biasQ = bq; gp.biasK = bk; gp.biasV = bv;
  gp.K = 1024; gp.scale = 1.f;
  gemm3<256,128,64,64,4,EPI_PROJ><<<dim3(8, 32, 3), 512, 73728, stream>>>(gp);

  // scores = q @ k^T * scale : per batch M=2048, N=2048, K=1024 (256 WGs)
  GP gs{};
  gs.A = qb; gs.batchA = 2097152; gs.lda = 1024;
  gs.B = kb; gs.batchB = 2097152; gs.ldb = 1024;
  gs.C = S;  gs.batchC = 4194304; gs.ldc = 2048;
  gs.K = 1024; gs.scale = 0.03125f;
  gemm3<256,256,128,64,2,EPI_SCALE><<<dim3(8, 8, 4), 512, 98304, stream>>>(gs);

  softmax_rows<<<8192, 256, 0, stream>>>(S);

  // out = P @ V : M=2048, N=1024, K=2048 per batch (256 WGs)
  GP gv{};
  gv.A = S;  gv.batchA = 4194304; gv.lda = 2048;
  gv.B = vT; gv.batchB = 2097152; gv.ldb = 2048;
  gv.C = (unsigned short*)d_out; gv.batchC = 2097152; gv.ldc = 1024;
  gv.K = 2048; gv.scale = 1.f;
  gemm3<256,128,64,64,2,EPI_OUT><<<dim3(8, 8, 4), 512, 73728, stream>>>(gv);
}

// Round 10
// 166.909 us; speedup vs baseline: 1.1548x; 1.0958x over previous
//
#include <hip/hip_runtime.h>

// ---------- types ----------
typedef __bf16 bf16x8 __attribute__((ext_vector_type(8)));
typedef float f32x4 __attribute__((ext_vector_type(4)));
typedef unsigned short u16x8 __attribute__((ext_vector_type(8)));

__device__ inline unsigned short f2bf(float f) {
  union { float f; unsigned u; } a; a.f = f;
  return (unsigned short)((a.u + 0x7fffu + ((a.u >> 16) & 1u)) >> 16); // RNE
}
__device__ inline float bf2f(unsigned short h) {
  union { unsigned u; float f; } a; a.u = ((unsigned)h) << 16;
  return a.f;
}

// ---------- fp32 -> bf16 conversion for Wq,Wk,Wv only (12 MB) ----------
__global__ __launch_bounds__(256) void cvtW(const float* __restrict__ Wq,
                                            const float* __restrict__ Wk,
                                            const float* __restrict__ Wv,
                                            unsigned short* __restrict__ Wb) {
  int i = blockIdx.x * 256 + threadIdx.x;   // 786432 float4 groups
  int idx = i >> 18;                        // 262144 float4 per W
  int off = i & 262143;
  const float* s = (idx == 0) ? Wq : ((idx == 1) ? Wk : Wv);
  float4 v = ((const float4*)s)[off];
  ushort4 o;
  o.x = f2bf(v.x); o.y = f2bf(v.y); o.z = f2bf(v.z); o.w = f2bf(v.w);
  ((ushort4*)(Wb + idx * 1048576))[off] = o;
}

#define G2L(gp, lp) __builtin_amdgcn_global_load_lds( \
    (const __attribute__((address_space(1))) void*)(gp), \
    (__attribute__((address_space(3))) void*)(lp), 16, 0, 0)

#define MFMA_(d, a, b) d = __builtin_amdgcn_mfma_f32_16x16x32_bf16(a, b, d, 0, 0, 0)
#define SB0() __builtin_amdgcn_sched_barrier(0)
#define LGKM(n) do { asm volatile("s_waitcnt lgkmcnt(" #n ")" ::: "memory"); SB0(); } while (0)
#define VMC(n) do { asm volatile("s_waitcnt vmcnt(" #n ")" ::: "memory"); SB0(); } while (0)

// =====================================================================
// gemmP: fused projection GEMM, A read DIRECTLY as fp32 from d_in.
// BM=256 BN=128 WMW=WNW=64, BK=32, 8 waves, 2 LDS buffers (80 KB ->
// 2 WGs/CU). A staged fp32 via G2L: row = 128B line, slot s holds
// k-group s^(line&7) (inverse-permuted source, both-sides rule);
// frag read = 2x ds_read_b128 fp32 -> cast bf16 in regs (compiler
// emits cvt_pk; same numerics as cvt6: r5/r7 passed). B bf16 via r9's
// verified row-paired layout. Kills cvt6's 144 MB X round-trip.
// Schedule: r4 rolling one-barrier; stage(t+1) at TOP of tile t.
// =====================================================================
struct PJ {
  const float* A0; const float* A1; const float* A2;
  const unsigned short* B;                  // Wb (3 matrices)
  unsigned short* outQ; unsigned short* outK; unsigned short* outV;
  const float* biasQ; const float* biasK; const float* biasV;
};

__global__ __launch_bounds__(512, 2) void gemmP(PJ p) {
  extern __shared__ char smem[];            // 81920: A 2x32768 | B 2x8192
  char* smA = smem;
  char* smB = smem + 65536;
  const int tid = threadIdx.x, lane = tid & 63, wid = tid >> 6;
  const int wm = wid >> 1, wn = wid & 1;

  // XCD swizzle, grid (8,32,3) = 768 WGs (768%8==0)
  int orig = blockIdx.x + 8 * (blockIdx.y + 32 * blockIdx.z);
  int wg = (orig & 7) * 96 + (orig >> 3);
  int bx = wg & 7; int t2 = wg >> 3; int by = t2 & 31; int z = t2 >> 5;
  const int m0 = by << 8, n0 = bx << 7;

  const float* Az = (z == 0) ? p.A0 : ((z == 1) ? p.A1 : p.A2);

  // staging sources (inverse-permuted)
  const int lineT = tid >> 3;
  const int sg = (tid & 7) ^ (lineT & 7);
  const char* srcA = (const char*)(Az + (long long)(m0 + lineT) * 1024) + (sg << 4);
  const int srowB = 2 * lineT + (sg >> 2);
  const char* srcB = (const char*)(p.B + (long long)z * 1048576
                                   + (long long)(n0 + srowB) * 1024) + ((sg & 3) << 4);

  // ds_read offsets. A (fp32, row=128B line): row R = wm*64+f*16+(lane&15),
  // R&7 == lane&7; byte = R*128 + ((2*(lane>>4)+j)^(lane&7))*16.
  const int aBase = (((wm << 6) + (lane & 15)) << 7);
  const int ax = lane & 7;
  const int ck0 = ((((lane >> 4) << 1) | 0) ^ ax) << 4;
  const int ck1 = ((((lane >> 4) << 1) | 1) ^ ax) << 4;
  // B (bf16 row-paired, r9-verified)
  const int rb2 = (lane & 15) >> 1;
  const int bBase = ((wn << 5) + rb2) << 7;
  const int bX = ((((lane & 1) << 2) | (lane >> 4)) ^ rb2) << 4;

  f32x4 acc[4][4];
#pragma unroll
  for (int i = 0; i < 4; ++i)
#pragma unroll
    for (int j = 0; j < 4; ++j) acc[i][j] = (f32x4){0.f, 0.f, 0.f, 0.f};

  f32x4 aLoF[2][2], aHiF[2][2];
  bf16x8 aLoB[2], aHiB[2], bLo[2], bHi[2];

  auto stage = [&](int t) {                 // 4 G2L (A fp32) + 1 G2L (B)
    char* dA = smA + ((t & 1) << 15) + (tid << 4);
    char* dB = smB + ((t & 1) << 13) + (tid << 4);
    const char* sA = srcA + (long long)t * 128;
#pragma unroll
    for (int c = 0; c < 4; ++c) G2L(sA + ((long long)c << 18), dA + (c << 13));
    G2L(srcB + (long long)t * 64, dB);
  };
  auto readA = [&](int b, int half, f32x4 (&dst)[2][2]) {   // 4 ds_read_b128
    const char* ra = smA + (b << 15) + aBase + (half << 12);
#pragma unroll
    for (int f = 0; f < 2; ++f) {
      dst[f][0] = *(const f32x4*)(ra + (f << 11) + ck0);
      dst[f][1] = *(const f32x4*)(ra + (f << 11) + ck1);
    }
  };
  auto readB = [&](int b, int half, bf16x8 (&dst)[2]) {     // 2 ds_read_b128
    const char* rb = smB + (b << 13) + bBase + (half << 11);
#pragma unroll
    for (int f = 0; f < 2; ++f)
      dst[f] = *(const bf16x8*)(rb + (f << 10) + bX);
  };
  auto cvtA = [&](f32x4 (&s)[2][2], bf16x8 (&d)[2]) {
#pragma unroll
    for (int f = 0; f < 2; ++f)
      d[f] = (bf16x8){(__bf16)s[f][0][0], (__bf16)s[f][0][1],
                      (__bf16)s[f][0][2], (__bf16)s[f][0][3],
                      (__bf16)s[f][1][0], (__bf16)s[f][1][1],
                      (__bf16)s[f][1][2], (__bf16)s[f][1][3]};
  };
  auto quadP = [&](int qa, int qb, bf16x8 (&A)[2], bf16x8 (&B)[2]) {
    __builtin_amdgcn_s_setprio(1);
#pragma unroll
    for (int mi = 0; mi < 2; ++mi)
#pragma unroll
      for (int ni = 0; ni < 2; ++ni)
        MFMA_(acc[qa * 2 + mi][qb * 2 + ni], A[mi], B[ni]);
    __builtin_amdgcn_s_setprio(0);
  };

  // ---- prologue ----
  stage(0);
  VMC(0);
  __builtin_amdgcn_s_barrier();
  readA(0, 0, aLoF); readB(0, 0, bLo);      // 4 + 2 outstanding
  SB0();

  const int NT = 32;
  for (int t = 0; t < NT; ++t) {
    if (t + 1 < NT) stage(t + 1);           // vmcnt ops, covered by tile body
    SB0();
    LGKM(2);                                // aLoF ready (bLo may remain)
    cvtA(aLoF, aLoB);                       // aLoF dies -> regs reusable
    readA(t & 1, 1, aHiF);                  // +4
    SB0();
    LGKM(4);                                // bLo ready (aHiF in flight)
    quadP(0, 0, aLoB, bLo);
    readB(t & 1, 1, bHi);                   // +2
    SB0();
    LGKM(2);                                // aHiF ready
    cvtA(aHiF, aHiB);
    quadP(1, 0, aHiB, bLo);
    LGKM(0);                                // bHi ready
    quadP(0, 1, aLoB, bHi);
    quadP(1, 1, aHiB, bHi);
    VMC(0);                                 // stage(t+1) landed
    __builtin_amdgcn_s_barrier();
    if (t + 1 < NT) { readA((t + 1) & 1, 0, aLoF); readB((t + 1) & 1, 0, bLo); }
    SB0();
  }

  // ---- epilogue: bias add; z<2 row-major; z==2 transposed vT[b][d][s] ----
  const int c0 = lane & 15, r0 = (lane >> 4) << 2;
  if (z < 2) {
    unsigned short* O = (z == 0) ? p.outQ : p.outK;
    const float* bias = (z == 0) ? p.biasQ : p.biasK;
#pragma unroll
    for (int mi = 0; mi < 4; ++mi) {
      const int grow = m0 + (wm << 6) + (mi << 4) + r0;
#pragma unroll
      for (int ni = 0; ni < 4; ++ni) {
        const int gcol = n0 + (wn << 6) + (ni << 4) + c0;
        const float bb = bias[gcol];
#pragma unroll
        for (int rr = 0; rr < 4; ++rr)
          O[(long long)(grow + rr) * 1024 + gcol] = f2bf(acc[mi][ni][rr] + bb);
      }
    }
  } else {
#pragma unroll
    for (int mi = 0; mi < 4; ++mi) {
      const int grow = m0 + (wm << 6) + (mi << 4) + r0;
      const int bb = grow >> 11, s = grow & 2047;
#pragma unroll
      for (int ni = 0; ni < 4; ++ni) {
        const int d = n0 + (wn << 6) + (ni << 4) + c0;
        const float ba = p.biasV[d];
        ushort4 pk;
        pk.x = f2bf(acc[mi][ni][0] + ba);
        pk.y = f2bf(acc[mi][ni][1] + ba);
        pk.z = f2bf(acc[mi][ni][2] + ba);
        pk.w = f2bf(acc[mi][ni][3] + ba);
        *(ushort4*)(p.outV + ((long long)bb << 21) + (long long)d * 2048 + s) = pk;
      }
    }
  }
}

// =====================================================================
// gemm2: r4-exact bf16 GEMM (BK=64, best measured for QK/PV).
// =====================================================================
#define EPI_SCALE 1
#define EPI_OUT 2

struct GP {
  const unsigned short* A;
  const unsigned short* B;
  unsigned short* C;            // bf16 (EPI_SCALE) or float* (EPI_OUT)
  long long batchA, batchB, batchC;
  int lda, ldb, ldc, K;
  float scale;
};

template<int BM, int BN, int WMW, int WNW, int EPI>
__global__ __launch_bounds__(512, 2) void gemm2(GP p) {
  constexpr int NWN = BN / WNW;
  constexpr int AMF = WMW / 16, BNF = WNW / 16;
  constexpr int AH = AMF / 2, BH = BNF / 2;
  constexpr int AF_N = AH * 2;
  constexpr int NBA = BM / 64, NBB = BN / 64;
  static_assert((BM / WMW) * NWN == 8, "8 waves");
  static_assert(BNF == 4, "lgkm immediates assume BNF==4");

  extern __shared__ char smem[];
  char* smA = smem;
  char* smB = smem + 2 * BM * 128;

  const int tid = threadIdx.x;
  const int lane = tid & 63;
  const int wid = tid >> 6;
  const int wm = wid / NWN, wn = wid % NWN;

  const int gx = gridDim.x, gy = gridDim.y;
  const int nwg = gx * gy * (int)gridDim.z;
  int orig = blockIdx.x + gx * (blockIdx.y + gy * blockIdx.z);
  int qq = nwg >> 3, rr_ = nwg & 7;
  int xcd = orig & 7, sl = orig >> 3;
  int wg = (xcd < rr_ ? xcd * (qq + 1) : rr_ * (qq + 1) + (xcd - rr_) * qq) + sl;
  int bx = wg % gx;
  int t2 = wg / gx;
  int by = t2 % gy;
  int z  = t2 / gy;

  const int m0 = by * BM, n0 = bx * BN;

  const long long lda2 = (long long)p.lda * 2;
  const long long ldb2 = (long long)p.ldb * 2;
  const char* Abase = (const char*)(p.A + (long long)z * p.batchA) + (long long)m0 * lda2;
  const char* Bbase = (const char*)(p.B + (long long)z * p.batchB) + (long long)n0 * ldb2;

  const int trow = tid >> 3;
  const int cs = (((tid & 7) ^ (trow & 7)) << 4);
  const char* srcA = Abase + (long long)trow * lda2 + cs;
  const char* srcB = Bbase + (long long)trow * ldb2 + cs;

  const int NT = p.K >> 6;

  const int aRowB = ((wm * WMW + (lane & 15)) << 7);
  const int bRowB = ((wn * WNW + (lane & 15)) << 7);
  const int csw = (lane & 7) << 4;
  const int ck0 = (((lane >> 4) << 4)) ^ csw;
  const int ck1 = ((((lane >> 4) << 4)) | 64) ^ csw;

  f32x4 acc[AMF][BNF];
#pragma unroll
  for (int i = 0; i < AMF; ++i)
#pragma unroll
    for (int j = 0; j < BNF; ++j) acc[i][j] = (f32x4){0.f, 0.f, 0.f, 0.f};

  bf16x8 aLo[AH][2], aHi[AH][2], bLo[BH][2], bHi[BH][2];

  auto stage = [&](int t) {
    char* dA = smA + (t & 1) * (BM * 128) + (tid << 4);
    char* dB = smB + (t & 1) * (BN * 128) + (tid << 4);
    const char* sA = srcA + (long long)t * 128;
    const char* sB = srcB + (long long)t * 128;
#pragma unroll
    for (int c = 0; c < NBA; ++c) G2L(sA + (long long)c * (lda2 << 6), dA + c * 8192);
#pragma unroll
    for (int c = 0; c < NBB; ++c) G2L(sB + (long long)c * (ldb2 << 6), dB + c * 8192);
  };
  auto readAh = [&](int t, int half, bf16x8 (&dst)[AH][2]) {
    const char* ra = smA + (t & 1) * (BM * 128) + aRowB + half * (AH * 2048);
#pragma unroll
    for (int mi = 0; mi < AH; ++mi) {
      dst[mi][0] = *(const bf16x8*)(ra + mi * 2048 + ck0);
      dst[mi][1] = *(const bf16x8*)(ra + mi * 2048 + ck1);
    }
  };
  auto readBh = [&](int t, int half, bf16x8 (&dst)[BH][2]) {
    const char* rb = smB + (t & 1) * (BN * 128) + bRowB + half * (BH * 2048);
#pragma unroll
    for (int ni = 0; ni < BH; ++ni) {
      dst[ni][0] = *(const bf16x8*)(rb + ni * 2048 + ck0);
      dst[ni][1] = *(const bf16x8*)(rb + ni * 2048 + ck1);
    }
  };
  auto quad = [&](int qa, int qb, bf16x8 (&A)[AH][2], bf16x8 (&B)[BH][2]) {
    __builtin_amdgcn_s_setprio(1);
#pragma unroll
    for (int mi = 0; mi < AH; ++mi)
#pragma unroll
      for (int ni = 0; ni < BH; ++ni) {
        MFMA_(acc[qa * AH + mi][qb * BH + ni], A[mi][0], B[ni][0]);
        MFMA_(acc[qa * AH + mi][qb * BH + ni], A[mi][1], B[ni][1]);
      }
    __builtin_amdgcn_s_setprio(0);
  };

  stage(0); stage(1);
  if constexpr (NBA + NBB == 8) VMC(8); else VMC(6);
  __builtin_amdgcn_s_barrier();
  readAh(0, 0, aLo); readBh(0, 0, bLo);
  SB0();

  for (int t = 0; t < NT; ++t) {
    readAh(t, 1, aHi);
    SB0();
    if constexpr (AF_N == 8) LGKM(8); else LGKM(4);
    quad(0, 0, aLo, bLo);
    readBh(t, 1, bHi);
    SB0();
    LGKM(4);
    quad(1, 0, aHi, bLo);
    LGKM(0);
    quad(0, 1, aLo, bHi);
    quad(1, 1, aHi, bHi);
    VMC(0);
    __builtin_amdgcn_s_barrier();
    if (t + 2 < NT) stage(t + 2);
    if (t + 1 < NT) { readAh(t + 1, 0, aLo); readBh(t + 1, 0, bLo); }
    SB0();
  }

  const int c0 = lane & 15;
  const int r0 = (lane >> 4) << 2;
  if constexpr (EPI == EPI_SCALE) {
    unsigned short* Cz = p.C + (long long)z * p.batchC;
#pragma unroll
    for (int mi = 0; mi < AMF; ++mi) {
      const int grow = m0 + wm * WMW + (mi << 4) + r0;
#pragma unroll
      for (int ni = 0; ni < BNF; ++ni) {
        const int gcol = n0 + wn * WNW + (ni << 4) + c0;
#pragma unroll
        for (int rr = 0; rr < 4; ++rr)
          Cz[(long long)(grow + rr) * p.ldc + gcol] = f2bf(acc[mi][ni][rr] * p.scale);
      }
    }
  } else {
    float* Cz = (float*)p.C + (long long)z * p.batchC;
#pragma unroll
    for (int mi = 0; mi < AMF; ++mi) {
      const int grow = m0 + wm * WMW + (mi << 4) + r0;
#pragma unroll
      for (int ni = 0; ni < BNF; ++ni) {
        const int gcol = n0 + wn * WNW + (ni << 4) + c0;
#pragma unroll
        for (int rr = 0; rr < 4; ++rr)
          Cz[(long long)(grow + rr) * p.ldc + gcol] = acc[mi][ni][rr] * p.scale;
      }
    }
  }
}

// ---------- row softmax over S[4][2048][2048] (bf16, in place) ----------
__global__ __launch_bounds__(256) void softmax_rows(unsigned short* __restrict__ S) {
  const size_t row = blockIdx.x;
  unsigned short* pp = S + row * 2048;
  const int t = threadIdx.x, lane = t & 63, wave = t >> 6;
  u16x8 h = ((const u16x8*)pp)[t];
  float x[8];
#pragma unroll
  for (int j = 0; j < 8; ++j) x[j] = bf2f(h[j]);
  float m = x[0];
#pragma unroll
  for (int j = 1; j < 8; ++j) m = fmaxf(m, x[j]);
#pragma unroll
  for (int off = 32; off >= 1; off >>= 1) m = fmaxf(m, __shfl_xor(m, off, 64));
  __shared__ float rmax[4], rsum[4];
  if (lane == 0) rmax[wave] = m;
  __syncthreads();
  m = fmaxf(fmaxf(rmax[0], rmax[1]), fmaxf(rmax[2], rmax[3]));
  float e[8], sum = 0.f;
#pragma unroll
  for (int j = 0; j < 8; ++j) { e[j] = __expf(x[j] - m); sum += e[j]; }
#pragma unroll
  for (int off = 32; off >= 1; off >>= 1) sum += __shfl_xor(sum, off, 64);
  if (lane == 0) rsum[wave] = sum;
  __syncthreads();
  sum = rsum[0] + rsum[1] + rsum[2] + rsum[3];
  const float inv = 1.f / sum;
  u16x8 o;
#pragma unroll
  for (int j = 0; j < 8; ++j) o[j] = f2bf(e[j] * inv);
  ((u16x8*)pp)[t] = o;
}

// ---------- launch ----------
extern "C" void kernel_launch(void* const* d_in, const int* in_sizes, int n_in,
                              void* d_out, int out_size, void* d_ws, size_t ws_size,
                              hipStream_t stream) {
  const float* q  = (const float*)d_in[0];
  const float* k  = (const float*)d_in[1];
  const float* v  = (const float*)d_in[2];
  const float* Wq = (const float*)d_in[3];
  const float* bq = (const float*)d_in[4];
  const float* Wk = (const float*)d_in[5];
  const float* bk = (const float*)d_in[6];
  const float* Wv = (const float*)d_in[7];
  const float* bv = (const float*)d_in[8];

  // workspace (u16 elems): S 32MB, Wb 6MB, qb 16MB, kb 16MB, vT 16MB = 86MB
  unsigned short* S  = (unsigned short*)d_ws;
  unsigned short* Wb = S + 16777216;
  unsigned short* qb = Wb + 3145728;
  unsigned short* kb = qb + 8388608;
  unsigned short* vT = kb + 8388608;

  (void)hipFuncSetAttribute((const void*)gemmP,
      hipFuncAttributeMaxDynamicSharedMemorySize, 81920);
  (void)hipFuncSetAttribute((const void*)gemm2<256,256,128,64,EPI_SCALE>,
      hipFuncAttributeMaxDynamicSharedMemorySize, 131072);
  (void)hipFuncSetAttribute((const void*)gemm2<256,128,64,64,EPI_OUT>,
      hipFuncAttributeMaxDynamicSharedMemorySize, 98304);

  cvtW<<<3072, 256, 0, stream>>>(Wq, Wk, Wv, Wb);

  // fused q/k/v projections, A read as fp32 (no X conversion pass):
  // per z, M=8192, N=1024, K=1024; 768 WGs, 2 WGs/CU
  PJ pj{};
  pj.A0 = q; pj.A1 = k; pj.A2 = v;
  pj.B = Wb;
  pj.outQ = qb; pj.outK = kb; pj.outV = vT;
  pj.biasQ = bq; pj.biasK = bk; pj.biasV = bv;
  gemmP<<<dim3(8, 32, 3), 512, 81920, stream>>>(pj);

  // scores = q @ k^T * scale : per batch M=2048, N=2048, K=1024 (256 WGs)
  GP gs{};
  gs.A = qb; gs.batchA = 2097152; gs.lda = 1024;
  gs.B = kb; gs.batchB = 2097152; gs.ldb = 1024;
  gs.C = S;  gs.batchC = 4194304; gs.ldc = 2048;
  gs.K = 1024; gs.scale = 0.03125f;
  gemm2<256,256,128,64,EPI_SCALE><<<dim3(8, 8, 4), 512, 131072, stream>>>(gs);

  softmax_rows<<<8192, 256, 0, stream>>>(S);

  // out = P @ V : M=2048, N=1024, K=2048 per batch (256 WGs)
  GP gv{};
  gv.A = S;  gv.batchA = 4194304; gv.lda = 2048;
  gv.B = vT; gv.batchB = 2097152; gv.ldb = 2048;
  gv.C = (unsigned short*)d_out; gv.batchC = 2097152; gv.ldc = 1024;
  gv.K = 2048; gv.scale = 1.f;
  gemm2<256,128,64,64,EPI_OUT><<<dim3(8, 8, 4), 512, 98304, stream>>>(gv);
}